// Round 3
// baseline (146.427 us; speedup 1.0000x reference)
//
#include <hip/hip_runtime.h>

// LocalAttention, MFMA bf16, round 10 = strip pipeline (T14 async-stage split).
// B=4, L=2048, H=16, E=D=64, window=64. fp32 in/out; bf16 MFMA; fp32 accumulate.
//
// Rounds 7-9 post-mortem: three attempts to batch staging loads inside one
// scheduling region (sched_barrier, branchless+fence, asm data anchor) all
// left VGPR_Count=52 and dur ~41-44 us/dispatch. No pipe >25% busy
// (VALU 21%, MfmaUtil 2.4%, HBM 36%); fillBuffer on the same trace streams
// 6.6 TB/s. Diagnosis: latency exposure from phase-structured tiny blocks --
// the load phase is short, correlated across waves, and never overlaps
// compute. The compiler wins every intra-region scheduling fight.
//
// Fix (guide T14, the one load-overlap pattern verified on this HW, +17% in
// m214): blocks own a STRIP of 4 consecutive q-tiles and software-pipeline:
//
//   prologue: load+pack tile 0 -> buf0
//   for s in 0..3:
//     issue K/V/Q loads for tile s+1        (VMEM in flight...)
//     QK + softmax of tile s from buf[s&1]  (...hidden under this)
//     barrier A
//     P -> overlay in Ks[s&1]; pack tile s+1 -> buf[(s+1)&1]  (vmcnt lands here)
//     barrier B
//     PV + store tile s
//
// Load->use distance = an entire compute phase + barrier, in PROGRAM ORDER.
// Double-buffered Ks/Vt: LDS = 2*(128*72 + 64*152)*2B = 75776 B -> 2 blocks/CU.
// launch_bounds(256,2) -> 256-VGPR cap; prefetch liveness (~80 regs) can't spill.
// Grid (L/256, H, B) = (8,16,4) = 512 blocks = 2/CU exactly.
// Per-tile math/layout identical to round 9 (index-masked softmax, clamped
// branchless addresses, P overlaid on current Ks after QK).

#define B_ 4
#define L_ 2048
#define H_ 16
#define E_ 64
#define D_ 64
#define ST 4
#define KS_STRIDE 72
#define VT_STRIDE 152
#define P_STRIDE 104
#define KS_SZ (128 * KS_STRIDE)
#define VT_SZ (64 * VT_STRIDE)

typedef __attribute__((ext_vector_type(8))) short short8;
typedef __attribute__((ext_vector_type(4))) float f32x4;

__device__ __forceinline__ unsigned int f2bf(float x) {
  unsigned int b = __float_as_uint(x);
  b += 0x7fffu + ((b >> 16) & 1u);   // RNE to bf16
  return b >> 16;
}
__device__ __forceinline__ unsigned int pack2(float a, float b) {
  return f2bf(a) | (f2bf(b) << 16);
}
__device__ __forceinline__ short8 pack8(const f32x4& a, const f32x4& b) {
  union { short8 s; uint4 u; } r;
  r.u = make_uint4(pack2(a[0], a[1]), pack2(a[2], a[3]),
                   pack2(b[0], b[1]), pack2(b[2], b[3]));
  return r.s;
}
__device__ __forceinline__ int clampL(int k) {
  return k < 0 ? 0 : (k > (L_ - 1) ? (L_ - 1) : k);
}

struct Pref {
  f32x4 kf[8];
  f32x4 va[4], vc[4];
  f32x4 qf[4];
};

__device__ __forceinline__ void issue_loads(Pref& p,
    const float* __restrict__ qg, const float* __restrict__ kg,
    const float* __restrict__ vg, int b, int h, int q0,
    int t, int wave, int col16, int quad) {
  const int kstart = q0 - 32;
  #pragma unroll
  for (int it = 0; it < 8; ++it) {
    int cid = t + it * 256;            // 128 rows x 16 float4-chunks
    int row = cid >> 4, ch = cid & 15;
    int key = clampL(kstart + row);
    p.kf[it] = *(const f32x4*)(kg + ((size_t)(b * L_ + key) * H_ + h) * E_ + ch * 4);
  }
  const int kp = t >> 2;               // key pair -> keys kstart+2kp, +2kp+1
  const int dq = t & 3;                // dim quarter
  {
    int k0 = clampL(kstart + 2 * kp);
    int k1 = clampL(kstart + 2 * kp + 1);
    const float* p0 = vg + ((size_t)(b * L_ + k0) * H_ + h) * D_ + dq * 16;
    const float* p1 = vg + ((size_t)(b * L_ + k1) * H_ + h) * D_ + dq * 16;
    #pragma unroll
    for (int i = 0; i < 4; ++i) p.va[i] = *(const f32x4*)(p0 + i * 4);
    #pragma unroll
    for (int i = 0; i < 4; ++i) p.vc[i] = *(const f32x4*)(p1 + i * 4);
  }
  {
    const float* pq = qg + ((size_t)(b * L_ + q0 + wave * 16 + col16) * H_ + h) * E_ + quad * 8;
    p.qf[0] = *(const f32x4*)pq;
    p.qf[1] = *(const f32x4*)(pq + 4);
    p.qf[2] = *(const f32x4*)(pq + 32);
    p.qf[3] = *(const f32x4*)(pq + 36);
  }
}

__device__ __forceinline__ void anchor(Pref& p) {
  // Data-dependence pin: loads cannot sink below a use of their results.
  asm volatile("" ::
      "v"(p.kf[0]), "v"(p.kf[1]), "v"(p.kf[2]), "v"(p.kf[3]),
      "v"(p.kf[4]), "v"(p.kf[5]), "v"(p.kf[6]), "v"(p.kf[7]),
      "v"(p.va[0]), "v"(p.va[1]), "v"(p.va[2]), "v"(p.va[3]),
      "v"(p.vc[0]), "v"(p.vc[1]), "v"(p.vc[2]), "v"(p.vc[3]),
      "v"(p.qf[0]), "v"(p.qf[1]), "v"(p.qf[2]), "v"(p.qf[3]));
  __builtin_amdgcn_sched_barrier(0);
}

__device__ __forceinline__ void pack_stage(const Pref& p,
    unsigned short* KsB, unsigned short* VtB,
    short8& qa0, short8& qa1, int t) {
  #pragma unroll
  for (int it = 0; it < 8; ++it) {
    int cid = t + it * 256;
    int row = cid >> 4, ch = cid & 15;
    f32x4 f = p.kf[it];
    *(uint2*)&KsB[row * KS_STRIDE + ch * 4] =
        make_uint2(pack2(f[0], f[1]), pack2(f[2], f[3]));
  }
  const int kp = t >> 2;
  const int dq = t & 3;
  #pragma unroll
  for (int i = 0; i < 4; ++i) {
    #pragma unroll
    for (int j = 0; j < 4; ++j) {
      int d = dq * 16 + i * 4 + j;
      *(unsigned int*)&VtB[d * VT_STRIDE + 2 * kp] = pack2(p.va[i][j], p.vc[i][j]);
    }
  }
  qa0 = pack8(p.qf[0], p.qf[1]);
  qa1 = pack8(p.qf[2], p.qf[3]);
}

__global__ __launch_bounds__(256, 2)
void local_attn_mfma(const float* __restrict__ qg,
                     const float* __restrict__ kg,
                     const float* __restrict__ vg,
                     float* __restrict__ og) {
  __shared__ __align__(16) unsigned short Ks[2][KS_SZ];   // [key_rel][dim]
  __shared__ __align__(16) unsigned short Vt[2][VT_SZ];   // [dim][key_rel]

  const int t = threadIdx.x;
  const int tile0 = blockIdx.x * ST;
  const int h = blockIdx.y;
  const int b = blockIdx.z;
  const int wave = t >> 6;
  const int lane = t & 63;
  const int col16 = lane & 15;
  const int quad = lane >> 4;

  // ---- Prologue: stage tile 0 into buf 0; zero Vt overhang pads (static) ----
  Pref pf;
  issue_loads(pf, qg, kg, vg, b, h, tile0 * 64, t, wave, col16, quad);
  short8 qa0, qa1;
  pack_stage(pf, &Ks[0][0], &Vt[0][0], qa0, qa1, t);
  // pad key cols 128..143 of both Vt buffers once (packs only touch cols 0..127)
  *(uint2*)&Vt[0][(t >> 2) * VT_STRIDE + 128 + (t & 3) * 4] = make_uint2(0u, 0u);
  *(uint2*)&Vt[1][(t >> 2) * VT_STRIDE + 128 + (t & 3) * 4] = make_uint2(0u, 0u);
  __syncthreads();

  #pragma unroll
  for (int s = 0; s < ST; ++s) {
    unsigned short* KsC = &Ks[s & 1][0];
    unsigned short* VtC = &Vt[s & 1][0];
    unsigned short* KsN = &Ks[(s + 1) & 1][0];
    unsigned short* VtN = &Vt[(s + 1) & 1][0];
    const int q0 = (tile0 + s) * 64;
    const int kstart = q0 - 32;

    // ---- Issue next tile's loads; they fly under this tile's QK+softmax ----
    if (s + 1 < ST) {
      issue_loads(pf, qg, kg, vg, b, h, q0 + 64, t, wave, col16, quad);
      anchor(pf);
    }

    // ---- QK: 5 key-tiles; B-frags from KsC (ds_read_b128) ----
    f32x4 acc[5];
    #pragma unroll
    for (int tt = 0; tt < 5; ++tt) {
      int krow = wave * 16 + tt * 16 + col16;   // B: n=key, k=quad*8+j (E-dim)
      short8 b0 = *(const short8*)&KsC[krow * KS_STRIDE + quad * 8];
      short8 b1 = *(const short8*)&KsC[krow * KS_STRIDE + quad * 8 + 32];
      f32x4 c = {0.f, 0.f, 0.f, 0.f};
      c = __builtin_amdgcn_mfma_f32_16x16x32_bf16(qa0, b0, c, 0, 0, 0);
      c = __builtin_amdgcn_mfma_f32_16x16x32_bf16(qa1, b1, c, 0, 0, 0);
      acc[tt] = c;
    }

    // ---- Mask + softmax in registers. C layout: row=quad*4+r, col=col16 ----
    #pragma unroll
    for (int r = 0; r < 4; ++r) {
      const int row_loc = quad * 4 + r;
      float x[5];
      #pragma unroll
      for (int tt = 0; tt < 5; ++tt) {
        int c_loc = tt * 16 + col16;                  // key rel to M-tile start
        int gkey = kstart + wave * 16 + c_loc;        // global key
        bool ok = (c_loc >= row_loc) && (c_loc < row_loc + 64) && (gkey >= 0) && (gkey < L_);
        x[tt] = ok ? acc[tt][r] * 0.125f : -1e30f;    // scale = 1/sqrt(64)
      }
      float m = fmaxf(fmaxf(fmaxf(x[0], x[1]), fmaxf(x[2], x[3])), x[4]);
      m = fmaxf(m, __shfl_xor(m, 1));
      m = fmaxf(m, __shfl_xor(m, 2));
      m = fmaxf(m, __shfl_xor(m, 4));
      m = fmaxf(m, __shfl_xor(m, 8));
      float sum = 0.f;
      #pragma unroll
      for (int tt = 0; tt < 5; ++tt) { x[tt] = __expf(x[tt] - m); sum += x[tt]; }
      sum += __shfl_xor(sum, 1);
      sum += __shfl_xor(sum, 2);
      sum += __shfl_xor(sum, 4);
      sum += __shfl_xor(sum, 8);
      float inv = 1.0f / sum;          // >= 32 valid keys -> sum >= 1
      #pragma unroll
      for (int tt = 0; tt < 5; ++tt) acc[tt][r] = x[tt] * inv;
    }

    // ---- Barrier A: all waves done reading KsC; it may now hold P / be repacked ----
    __syncthreads();

    // ---- P -> overlay in KsC (bf16, A-layout), zero-pad cols 80..95 ----
    unsigned short* Pw = &KsC[wave * 16 * P_STRIDE];
    *(uint2*)&Pw[col16 * P_STRIDE + 80 + quad * 4] = make_uint2(0u, 0u);
    #pragma unroll
    for (int tt = 0; tt < 5; ++tt)
      #pragma unroll
      for (int r = 0; r < 4; ++r)
        Pw[(quad * 4 + r) * P_STRIDE + tt * 16 + col16] = (unsigned short)f2bf(acc[tt][r]);

    // ---- Pack next tile into the other buffers (vmcnt for prefetch lands here) ----
    short8 qn0, qn1;
    if (s + 1 < ST) pack_stage(pf, KsN, VtN, qn0, qn1, t);

    // ---- Barrier B: P + next-tile staging visible ----
    __syncthreads();

    // ---- PV: A=P[16 x 96], B=VtC keys [wave*16, wave*16+96) x 64 dims ----
    f32x4 oacc[4];
    #pragma unroll
    for (int nt = 0; nt < 4; ++nt) oacc[nt] = (f32x4){0.f, 0.f, 0.f, 0.f};
    #pragma unroll
    for (int ks = 0; ks < 3; ++ks) {
      short8 pa = *(const short8*)&Pw[col16 * P_STRIDE + ks * 32 + quad * 8];
      #pragma unroll
      for (int nt = 0; nt < 4; ++nt) {
        short8 vb = *(const short8*)&VtC[(nt * 16 + col16) * VT_STRIDE + wave * 16 + ks * 32 + quad * 8];
        oacc[nt] = __builtin_amdgcn_mfma_f32_16x16x32_bf16(pa, vb, oacc[nt], 0, 0, 0);
      }
    }

    // ---- Store O (fp32). C layout: row=quad*4+r (query), col=col16 (dim) ----
    #pragma unroll
    for (int r = 0; r < 4; ++r) {
      int q = q0 + wave * 16 + quad * 4 + r;
      float* orow = og + ((size_t)(b * L_ + q) * H_ + h) * D_;
      #pragma unroll
      for (int nt = 0; nt < 4; ++nt)
        orow[nt * 16 + col16] = oacc[nt][r];
    }

    if (s + 1 < ST) { qa0 = qn0; qa1 = qn1; }
  }
}

extern "C" void kernel_launch(void* const* d_in, const int* in_sizes, int n_in,
                              void* d_out, int out_size, void* d_ws, size_t ws_size,
                              hipStream_t stream) {
  const float* q = (const float*)d_in[0];
  const float* k = (const float*)d_in[1];
  const float* v = (const float*)d_in[2];
  float* o = (float*)d_out;
  dim3 grid(L_ / (64 * ST), H_, B_);
  local_attn_mfma<<<grid, dim3(256), 0, stream>>>(q, k, v, o);
}